// Round 6
// baseline (1495.439 us; speedup 1.0000x reference)
//
#include <hip/hip_runtime.h>
#include <hip/hip_bf16.h>
#include <math.h>

#define INF_ 1e10f
#define LGKM0() asm volatile("s_waitcnt lgkmcnt(0)" ::: "memory")

static constexpr int B_  = 64;
static constexpr int N_  = 197;
static constexpr int C_  = 768;
static constexpr int H_  = 12;
static constexpr int T_  = 196;   // N-1 tokens clustered
static constexpr int KC_ = 98;    // NUM_CLUSTERS
static constexpr int KT_ = 99;    // NUM_CLUSTERS + 1
static constexpr int HF_ = 3072;

typedef __attribute__((ext_vector_type(8))) short short8v;
typedef __attribute__((ext_vector_type(4))) float f32x4;
typedef __attribute__((ext_vector_type(4))) int int4v;

__device__ __forceinline__ float wave_sum(float v){
#pragma unroll
  for(int o=32;o;o>>=1) v += __shfl_down(v,o);
  return v;
}

__device__ __forceinline__ ushort f2bf(float v){
  __hip_bfloat16 t = __float2bfloat16(v);
  return *reinterpret_cast<const ushort*>(&t);
}

// ---------------- LayerNorm (row = 768, block = 256); writes f32 and/or bf16 ----------------
__global__ __launch_bounds__(256) void ln_kernel(const float* __restrict__ in,
    const float* __restrict__ g, const float* __restrict__ bb,
    float* __restrict__ outf, __hip_bfloat16* __restrict__ outb){
  int row = blockIdx.x;
  const float* xr = in + (size_t)row*C_;
  int tid = threadIdx.x;
  float v0=xr[tid], v1=xr[tid+256], v2=xr[tid+512];
  __shared__ float sred[4];
  __shared__ float smean, svar;
  float s = wave_sum(v0+v1+v2);
  int w=tid>>6, l=tid&63;
  if(l==0) sred[w]=s;
  __syncthreads();
  if(tid==0) smean = (sred[0]+sred[1]+sred[2]+sred[3])/(float)C_;
  __syncthreads();
  float m = smean;
  float d0=v0-m, d1=v1-m, d2=v2-m;
  float q = wave_sum(d0*d0+d1*d1+d2*d2);
  if(l==0) sred[w]=q;
  __syncthreads();
  if(tid==0) svar = (sred[0]+sred[1]+sred[2]+sred[3])/(float)C_;
  __syncthreads();
  float sq = sqrtf(svar + 1e-5f);
  float y0 = d0/sq*g[tid]     + bb[tid];
  float y1 = d1/sq*g[tid+256] + bb[tid+256];
  float y2 = d2/sq*g[tid+512] + bb[tid+512];
  if(outf){
    float* orow = outf + (size_t)row*C_;
    orow[tid]=y0; orow[tid+256]=y1; orow[tid+512]=y2;
  }
  if(outb){
    __hip_bfloat16* orow = outb + (size_t)row*C_;
    orow[tid]=__float2bfloat16(y0); orow[tid+256]=__float2bfloat16(y1); orow[tid+512]=__float2bfloat16(y2);
  }
}

// ---------------- Wm[c][d] = mean over heads of w_qkv k-columns (for metric) ----------------
__global__ __launch_bounds__(256) void wmean_kernel(const float* __restrict__ w,
    float* __restrict__ Wm){
  int t = blockIdx.x*256 + threadIdx.x;   // t = c*64+d
  if(t >= C_*64) return;
  int c = t>>6, d = t&63;
  const float* p = w + (size_t)c*(3*C_) + C_ + d;
  float s=0.f;
#pragma unroll
  for(int h=0;h<H_;h++) s += p[h*64];
  Wm[t] = s*(1.0f/12.0f);
}

// ---------------- transpose f32 [K,N] -> bf16 [N,K] ----------------
__global__ __launch_bounds__(256) void transpose_bf16(const float* __restrict__ w,
    __hip_bfloat16* __restrict__ wt, int K, int N){
  __shared__ float tile[32][33];
  int n0 = blockIdx.x*32, k0 = blockIdx.y*32;
  int tx = threadIdx.x&31, ty = threadIdx.x>>5;
  for(int r=ty;r<32;r+=8) tile[r][tx] = w[(size_t)(k0+r)*N + n0+tx];
  __syncthreads();
  for(int r=ty;r<32;r+=8) wt[(size_t)(n0+r)*K + k0+tx] = __float2bfloat16(tile[tx][r]);
}

// ---------------- bf16 MFMA GEMM: C = A[MxK] @ Bt[NxK]^T, f32 accum ----------------
// EPI: 1/3 = (res+v)+bias -> f32; 2 = v+bias, exact GELU -> bf16; 4 = store bf16
template<int EPI>
__global__ __launch_bounds__(256) void gemm_bf16(const ushort* __restrict__ A,
    const ushort* __restrict__ Bt, const float* __restrict__ bias,
    const float* __restrict__ res, void* __restrict__ Cout,
    int M, int N, int K){
  constexpr int BM=128, BN=128, BK=32;
  __shared__ ushort As[BM][40];
  __shared__ ushort Bs[BN][40];
  int tid = threadIdx.x;
  int bm = blockIdx.y*BM, bn = blockIdx.x*BN;
  int w = tid>>6, l = tid&63;
  int wm = (w>>1)*64, wn = (w&1)*64;
  int lr = l&15, lc = l>>4;           // frag row/col, k-chunk
  f32x4 acc[4][4] = {};
  for(int k0=0;k0<K;k0+=BK){
#pragma unroll
    for(int s=0;s<2;s++){
      int cid = tid + s*256;          // 512 chunks: row=cid>>2, ch=cid&3
      int r = cid>>2, ch = cid&3;
      int4v va = {0,0,0,0};
      if(bm+r < M) va = *reinterpret_cast<const int4v*>(A + (size_t)(bm+r)*K + k0 + ch*8);
      *reinterpret_cast<int4v*>(&As[r][ch*8]) = va;
      int4v vb = *reinterpret_cast<const int4v*>(Bt + (size_t)(bn+r)*K + k0 + ch*8);
      *reinterpret_cast<int4v*>(&Bs[r][ch*8]) = vb;
    }
    __syncthreads();
    short8v af[4], bfr[4];
#pragma unroll
    for(int f=0; f<4; f++){
      af[f]  = *reinterpret_cast<const short8v*>(&As[wm + f*16 + lr][lc*8]);
      bfr[f] = *reinterpret_cast<const short8v*>(&Bs[wn + f*16 + lr][lc*8]);
    }
#pragma unroll
    for(int i=0;i<4;i++)
#pragma unroll
      for(int j=0;j<4;j++)
        acc[i][j] = __builtin_amdgcn_mfma_f32_16x16x32_bf16(af[i], bfr[j], acc[i][j], 0,0,0);
    __syncthreads();
  }
#pragma unroll
  for(int i=0;i<4;i++){
    int rbase = bm + wm + i*16 + lc*4;
#pragma unroll
    for(int j=0;j<4;j++){
      int col = bn + wn + j*16 + lr;
#pragma unroll
      for(int r=0;r<4;r++){
        int row = rbase + r;
        if(row >= M) continue;
        size_t idx = (size_t)row*N + col;
        float v = acc[i][j][r];
        if constexpr(EPI==1 || EPI==3) ((float*)Cout)[idx] = (res[idx] + v) + bias[col];
        if constexpr(EPI==2){
          v += bias[col];
          v = 0.5f*v*(1.0f+erff(v*0.70710678118654752f));
          ((__hip_bfloat16*)Cout)[idx] = __float2bfloat16(v);
        }
        if constexpr(EPI==4) ((__hip_bfloat16*)Cout)[idx] = __float2bfloat16(v);
      }
    }
  }
}

// ---------------- metric = h @ Wm (f32, sequential k), normalize, drop cls ----------------
__global__ __launch_bounds__(64) void metric_gemm(const float* __restrict__ h,
    const float* __restrict__ Wm, float* __restrict__ mnorm){
  int row = blockIdx.x;
  int b = row / N_, n = row - b*N_;
  __shared__ float hs[C_];
  int l = threadIdx.x;
  for(int c=l;c<C_;c+=64) hs[c]=h[(size_t)row*C_+c];
  __syncthreads();
  float acc=0.f;
#pragma unroll 4
  for(int c=0;c<C_;c++) acc = fmaf(hs[c], Wm[c*64+l], acc);
  float q=acc*acc;
#pragma unroll
  for(int o=32;o;o>>=1) q += __shfl_xor(q,o);
  float nrm = sqrtf(q);
  if(n>=1) mnorm[((size_t)b*T_+(n-1))*64+l] = acc/nrm;
}

// ---------------- MFMA attention: one block per (b,h), 4 waves, q-tiles of 16 ----------------
__global__ __launch_bounds__(256) void attn_mfma(const ushort* __restrict__ qkv,
    const float* __restrict__ attn_size, __hip_bfloat16* __restrict__ xa){
  int h = blockIdx.x, b = blockIdx.y;
  __shared__ ushort Ks[208][72];
  __shared__ ushort VsT[64][232];
  __shared__ ushort Ps[4][16][232];
  __shared__ float lsz[208];
  int tid = threadIdx.x;
  int w = tid>>6, l = tid&63;
  int lr = l&15, lc = l>>4;
  const size_t QROW = 3*C_;
  for(int t=tid; t<208*64; t+=256){
    int n=t>>6, d=t&63;
    ushort v = 0;
    if(n<197) v = qkv[((size_t)(b*N_+n))*QROW + C_ + h*64 + d];
    Ks[n][d] = v;
  }
  for(int t=tid; t<232*64; t+=256){
    int n=t>>6, d=t&63;
    ushort v = 0;
    if(n<197) v = qkv[((size_t)(b*N_+n))*QROW + 2*C_ + h*64 + d];
    VsT[d][n] = v;
  }
  for(int t=tid;t<208;t+=256) lsz[t] = (t<197)? logf(attn_size[b*N_+t]) : 0.f;
  for(int c=l; c<16*24; c+=64){ int rr=c/24, cc=208+(c%24); Ps[w][rr][cc]=0; }
  __syncthreads();

  for(int qt=w; qt<13; qt+=4){
    int qrow = min(qt*16 + lr, 196);
    const ushort* qp = qkv + ((size_t)(b*N_+qrow))*QROW + h*64;
    short8v aq0 = *reinterpret_cast<const short8v*>(qp + lc*8);
    short8v aq1 = *reinterpret_cast<const short8v*>(qp + 32 + lc*8);
    float sc[13][4];
#pragma unroll
    for(int t=0;t<13;t++){
      short8v b0 = *reinterpret_cast<const short8v*>(&Ks[t*16+lr][lc*8]);
      short8v b1 = *reinterpret_cast<const short8v*>(&Ks[t*16+lr][32+lc*8]);
      f32x4 a = {0.f,0.f,0.f,0.f};
      a = __builtin_amdgcn_mfma_f32_16x16x32_bf16(aq0, b0, a, 0,0,0);
      a = __builtin_amdgcn_mfma_f32_16x16x32_bf16(aq1, b1, a, 0,0,0);
      float ls = lsz[t*16+lr];
      bool mask = (t==12) && (lr>=5);
#pragma unroll
      for(int r=0;r<4;r++) sc[t][r] = mask ? -1e30f : (a[r]*0.125f + ls);
    }
    float rsum[4];
#pragma unroll
    for(int r=0;r<4;r++){
      float m=-1e30f;
#pragma unroll
      for(int t=0;t<13;t++) m = fmaxf(m, sc[t][r]);
#pragma unroll
      for(int o=1;o<16;o<<=1) m = fmaxf(m, __shfl_xor(m,o));
      float s=0.f;
#pragma unroll
      for(int t=0;t<13;t++){ float p=expf(sc[t][r]-m); sc[t][r]=p; s+=p; }
#pragma unroll
      for(int o=1;o<16;o<<=1) s += __shfl_xor(s,o);
      rsum[r]=s;
    }
#pragma unroll
    for(int t=0;t<13;t++)
#pragma unroll
      for(int r=0;r<4;r++)
        Ps[w][lc*4+r][t*16+lr] = f2bf(sc[t][r]);
    LGKM0();
    short8v ap[7];
#pragma unroll
    for(int ks=0;ks<7;ks++) ap[ks] = *reinterpret_cast<const short8v*>(&Ps[w][lr][ks*32 + lc*8]);
#pragma unroll
    for(int f=0; f<4; f++){
      f32x4 o = {0.f,0.f,0.f,0.f};
#pragma unroll
      for(int ks=0;ks<7;ks++){
        short8v bv = *reinterpret_cast<const short8v*>(&VsT[f*16+lr][ks*32 + lc*8]);
        o = __builtin_amdgcn_mfma_f32_16x16x32_bf16(ap[ks], bv, o, 0,0,0);
      }
#pragma unroll
      for(int r=0;r<4;r++){
        int q = qt*16 + lc*4 + r;
        if(q<197) xa[((size_t)(b*N_+q))*C_ + h*64 + f*16 + lr] = __float2bfloat16(o[r]/rsum[r]);
      }
    }
  }
}

// ---------------- agglomerative clustering: init with 256 threads, loop on 1 wave ----------------
// Wave-synchronous iteration (no __syncthreads in the 98-step loop). Update formulas are
// identical to the verified 4-wave version; only the parallel decomposition changed.
// Hazard analysis: in phase C/D, D[i][k] / D[j][k] / rowmin[k] / labels[k] are read and
// written ONLY by the lane owning column k (k % 64), so no cross-lane ordering is needed
// within the phase; cross-lane visibility (rowarg[i], rescan of row i, rcnt) is handled
// by s_waitcnt lgkmcnt(0) at phase boundaries (wave executes in lockstep).
__global__ __launch_bounds__(256) void cluster_kernel(const float* __restrict__ mnorm,
    int* __restrict__ labs_ws, float* __restrict__ labs_out){
  int b = blockIdx.x;
  __shared__ float D[T_][T_+1];
  __shared__ float sizes[T_];
  __shared__ int   labels[T_];
  __shared__ int   active[T_];
  __shared__ float rowmin[T_];
  __shared__ int   rowarg[T_];
  __shared__ int   rlist[T_];
  __shared__ int   rcnt;
  int tid = threadIdx.x;
  const float* mb = mnorm + (size_t)b*T_*64;

  for(int t=tid;t<T_*T_;t+=256){
    int r=t/T_, c=t%T_;
    float dot=0.0f;
    for(int d=0;d<64;d++) dot += mb[r*64+d]*mb[c*64+d];
    D[r][c] = (r==c) ? INF_ : (1.0f - dot);
  }
  for(int t=tid;t<T_;t+=256){ sizes[t]=1.0f; labels[t]=t; active[t]=1; }
  __syncthreads();
  if(tid<T_){
    float bvv=INF_; int ba=0;
    for(int c=0;c<T_;c++){ float v=D[tid][c]; if(v<bvv){ bvv=v; ba=c; } }
    rowmin[tid]=bvv; rowarg[tid]=ba;
  }
  __syncthreads();
  if(tid>=64) return;           // single wave from here on (after the barrier -> safe)
  int l = tid;

  for(int it=0; it<T_-KC_; it++){
    // --- phase A: argmin over (rowmin[r], r), in-register butterfly ---
    float bv=INF_; int bi=0x7fffffff;
    for(int k=l;k<T_;k+=64){ float v=rowmin[k]; if(v<bv){ bv=v; bi=k; } }   // ascending k -> first idx
#pragma unroll
    for(int o=32;o;o>>=1){
      float ov=__shfl_xor(bv,o); int oi=__shfl_xor(bi,o);
      if(ov<bv || (ov==bv && oi<bi)){ bv=ov; bi=oi; }
    }
    int i = bi;
    int j = rowarg[i];          // LDS broadcast
    float ni = sizes[i], nj = sizes[j];
    if(l==0) rcnt = 0;
    LGKM0();
    // --- phase C/D: Lance-Williams update + incremental rowmin (lane owns cols k%64==l) ---
    for(int k=l;k<T_;k+=64){
      float di=D[i][k], dj=D[j][k];
      float oldrm=rowmin[k]; int oldarg=rowarg[k];
      int act=active[k]; int lab=labels[k];
      bool kact = (k!=i) && (k!=j) && (act!=0);
      float nd = kact ? (ni*di + nj*dj) / (ni+nj) : INF_;
      D[i][k]=nd; D[k][i]=nd; D[j][k]=INF_; D[k][j]=INF_;
      if(lab==j) labels[k]=i;
      if(k==i){
        int p=atomicAdd(&rcnt,1); rlist[p]=k;                 // row i: full rescan
      } else if(k==j){
        rowmin[k]=INF_; rowarg[k]=0;
      } else if(kact){
        if(oldarg==i){
          if(nd<=oldrm) rowmin[k]=nd;
          else { int p=atomicAdd(&rcnt,1); rlist[p]=k; }
        } else if(oldarg==j){
          if(nd<=oldrm){ rowmin[k]=nd; rowarg[k]=i; }
          else { int p=atomicAdd(&rcnt,1); rlist[p]=k; }
        } else {
          if(nd<oldrm || (nd==oldrm && i<oldarg)){ rowmin[k]=nd; rowarg[k]=i; }
        }
      }
    }
    if(l==0){ sizes[i]=ni+nj; active[j]=0; }
    LGKM0();
    // --- phase E: full rescans (whole wave per row, few rows) ---
    int nr = rcnt;
    for(int q=0;q<nr;q++){
      int rr = rlist[q];
      float v=INF_; int c=0x7fffffff;
      for(int cc=l; cc<T_; cc+=64){
        float vv=D[rr][cc];
        if(vv<v){ v=vv; c=cc; }
      }
#pragma unroll
      for(int o=32;o;o>>=1){
        float ov=__shfl_xor(v,o); int oc=__shfl_xor(c,o);
        if(ov<v || (ov==v && oc<c)){ v=ov; c=oc; }
      }
      if(l==0){ rowmin[rr]=v; rowarg[rr]=c; }
    }
    LGKM0();
  }

  if(l==0){
    int c=0;
    for(int t=0;t<T_;t++){ c += active[t]; rlist[t]=c-1; }    // rlist = rank
    labs_ws[b*N_]=0; labs_out[b*N_]=0.0f;
  }
  LGKM0();
  for(int t=l;t<T_;t+=64){
    int lab = rlist[labels[t]] + 1;
    labs_ws[b*N_+1+t] = lab;
    labs_out[b*N_+1+t] = (float)lab;
  }
}

// ---------------- weighted-average merge: one block per (chunk of 256 ch, b) ----------------
// Thread owns channel c; scatter-accumulate x1*sz into acc[lab[n]][tid] over n ascending
// (unique column owner -> no races; ascending n == reference accumulation order).
__global__ __launch_bounds__(256) void merge_kernel(const float* __restrict__ x1,
    const float* __restrict__ asz, const int* __restrict__ labs,
    float* __restrict__ x2, float* __restrict__ size_out){
  int chunk = blockIdx.x;     // 0..2 (C_/256)
  int b = blockIdx.y;
  __shared__ float acc[KT_][256];
  __shared__ int   lab[N_];
  __shared__ float sz[N_];
  __shared__ float ssum[KT_];
  int tid = threadIdx.x;
  for(int t=tid;t<N_;t+=256){ lab[t]=labs[b*N_+t]; sz[t]=asz[b*N_+t]; }
#pragma unroll
  for(int k=0;k<KT_;k++) acc[k][tid]=0.f;
  __syncthreads();
  if(tid<KT_){
    float s=0.f;
    for(int n=0;n<N_;n++) if(lab[n]==tid) s += sz[n];
    ssum[tid]=s;
  }
  int c = chunk*256 + tid;
  const float* xb = x1 + (size_t)b*N_*C_ + c;
  for(int n=0;n<N_;n++){
    float v = xb[(size_t)n*C_];
    int k = lab[n];
    acc[k][tid] += v * sz[n];
  }
  __syncthreads();
  for(int k=0;k<KT_;k++)
    x2[((size_t)(b*KT_+k))*C_ + c] = acc[k][tid] / ssum[k];
  if(chunk==0 && tid<KT_) size_out[b*KT_+tid] = ssum[tid];
}

extern "C" void kernel_launch(void* const* d_in, const int* in_sizes, int n_in,
                              void* d_out, int out_size, void* d_ws, size_t ws_size,
                              hipStream_t stream){
  const float* x      = (const float*)d_in[0];
  const float* asz    = (const float*)d_in[1];
  const float* n1_g   = (const float*)d_in[2];
  const float* n1_b   = (const float*)d_in[3];
  const float* w_qkv  = (const float*)d_in[4];
  const float* w_proj = (const float*)d_in[5];
  const float* b_proj = (const float*)d_in[6];
  const float* n2_g   = (const float*)d_in[7];
  const float* n2_b   = (const float*)d_in[8];
  const float* w_fc1  = (const float*)d_in[9];
  const float* b_fc1  = (const float*)d_in[10];
  const float* w_fc2  = (const float*)d_in[11];
  const float* b_fc2  = (const float*)d_in[12];

  const size_t ROWS = (size_t)B_*N_;        // 12608
  const size_t M2   = (size_t)B_*KT_;       // 6336
  float* ws = (float*)d_ws;

  float* h     = ws;                                    // [ROWS*C] f32 LN1 out; later x1
  float* qkvR  = h + ROWS*C_;                           // region, ROWS*3C floats
  __hip_bfloat16* qkvb = (__hip_bfloat16*)qkvR;         // qkv as bf16 (attn-only consumer)
  float* x2    = qkvR;                                  // [M2*C] alias (qkv dead by merge)
  __hip_bfloat16* h2b = (__hip_bfloat16*)(qkvR + M2*C_);
  __hip_bfloat16* h3b = (__hip_bfloat16*)(qkvR + M2*C_ + M2*C_/2);
  __hip_bfloat16* hb  = (__hip_bfloat16*)(qkvR + ROWS*3*C_);      // [ROWS*C] bf16; later xa
  __hip_bfloat16* xa  = hb;
  float* mnorm = (float*)(hb) + ROWS*C_/2;
  float* Wm    = mnorm + (size_t)B_*T_*64;
  __hip_bfloat16* wqkvT = (__hip_bfloat16*)(Wm + C_*64);
  __hip_bfloat16* wprojT= (__hip_bfloat16*)((float*)wqkvT + (size_t)3*C_*C_/2);
  __hip_bfloat16* wfc1T = (__hip_bfloat16*)((float*)wprojT + (size_t)C_*C_/2);
  __hip_bfloat16* wfc2T = (__hip_bfloat16*)((float*)wfc1T + (size_t)C_*HF_/2);
  int*   labs  = (int*)((float*)wfc2T + (size_t)HF_*C_/2);
  float* x1    = h;

  float* out     = (float*)d_out;
  float* out_sz  = out + M2*C_;
  float* out_lab = out_sz + M2;

  // prep
  ln_kernel<<<dim3((unsigned)ROWS),256,0,stream>>>(x, n1_g, n1_b, h, hb);
  wmean_kernel<<<dim3(192),256,0,stream>>>(w_qkv, Wm);
  transpose_bf16<<<dim3(72,24),256,0,stream>>>(w_qkv, wqkvT, C_, 3*C_);
  transpose_bf16<<<dim3(24,24),256,0,stream>>>(w_proj, wprojT, C_, C_);
  transpose_bf16<<<dim3(96,24),256,0,stream>>>(w_fc1, wfc1T, C_, HF_);
  transpose_bf16<<<dim3(24,96),256,0,stream>>>(w_fc2, wfc2T, HF_, C_);

  // attention block
  gemm_bf16<4><<<dim3(18,99),256,0,stream>>>((const ushort*)hb, (const ushort*)wqkvT,
      nullptr, nullptr, qkvb, (int)ROWS, 3*C_, C_);
  metric_gemm<<<dim3((unsigned)ROWS),64,0,stream>>>(h, Wm, mnorm);
  attn_mfma<<<dim3(H_,B_),256,0,stream>>>((const ushort*)qkvb, asz, xa);
  gemm_bf16<1><<<dim3(6,99),256,0,stream>>>((const ushort*)xa, (const ushort*)wprojT,
      b_proj, x, x1, (int)ROWS, C_, C_);

  // clustering + merge
  cluster_kernel<<<dim3(B_),256,0,stream>>>(mnorm, labs, out_lab);
  merge_kernel<<<dim3(3,B_),256,0,stream>>>(x1, asz, labs, x2, out_sz);

  // MLP
  ln_kernel<<<dim3((unsigned)M2),256,0,stream>>>(x2, n2_g, n2_b, nullptr, h2b);
  gemm_bf16<2><<<dim3(24,50),256,0,stream>>>((const ushort*)h2b, (const ushort*)wfc1T,
      b_fc1, nullptr, h3b, (int)M2, HF_, C_);
  gemm_bf16<3><<<dim3(6,50),256,0,stream>>>((const ushort*)h3b, (const ushort*)wfc2T,
      b_fc2, x2, out, (int)M2, C_, HF_);
}

// Round 8
// 1218.456 us; speedup vs baseline: 1.2273x; 1.2273x over previous
//
#include <hip/hip_runtime.h>
#include <hip/hip_bf16.h>
#include <math.h>

#define INF_ 1e10f
#define LGKM0() asm volatile("s_waitcnt lgkmcnt(0)" ::: "memory")

static constexpr int B_  = 64;
static constexpr int N_  = 197;
static constexpr int C_  = 768;
static constexpr int H_  = 12;
static constexpr int T_  = 196;   // N-1 tokens clustered
static constexpr int KC_ = 98;    // NUM_CLUSTERS
static constexpr int KT_ = 99;    // NUM_CLUSTERS + 1
static constexpr int HF_ = 3072;

typedef __attribute__((ext_vector_type(8))) short short8v;
typedef __attribute__((ext_vector_type(4))) float f32x4;
typedef __attribute__((ext_vector_type(4))) int int4v;

__device__ __forceinline__ float wave_sum(float v){
#pragma unroll
  for(int o=32;o;o>>=1) v += __shfl_down(v,o);
  return v;
}

__device__ __forceinline__ ushort f2bf(float v){
  __hip_bfloat16 t = __float2bfloat16(v);
  return *reinterpret_cast<const ushort*>(&t);
}

// ---------------- LayerNorm (row = 768, block = 256); writes f32 and/or bf16 ----------------
__global__ __launch_bounds__(256) void ln_kernel(const float* __restrict__ in,
    const float* __restrict__ g, const float* __restrict__ bb,
    float* __restrict__ outf, __hip_bfloat16* __restrict__ outb){
  int row = blockIdx.x;
  const float* xr = in + (size_t)row*C_;
  int tid = threadIdx.x;
  float v0=xr[tid], v1=xr[tid+256], v2=xr[tid+512];
  __shared__ float sred[4];
  __shared__ float smean, svar;
  float s = wave_sum(v0+v1+v2);
  int w=tid>>6, l=tid&63;
  if(l==0) sred[w]=s;
  __syncthreads();
  if(tid==0) smean = (sred[0]+sred[1]+sred[2]+sred[3])/(float)C_;
  __syncthreads();
  float m = smean;
  float d0=v0-m, d1=v1-m, d2=v2-m;
  float q = wave_sum(d0*d0+d1*d1+d2*d2);
  if(l==0) sred[w]=q;
  __syncthreads();
  if(tid==0) svar = (sred[0]+sred[1]+sred[2]+sred[3])/(float)C_;
  __syncthreads();
  float sq = sqrtf(svar + 1e-5f);
  float y0 = d0/sq*g[tid]     + bb[tid];
  float y1 = d1/sq*g[tid+256] + bb[tid+256];
  float y2 = d2/sq*g[tid+512] + bb[tid+512];
  if(outf){
    float* orow = outf + (size_t)row*C_;
    orow[tid]=y0; orow[tid+256]=y1; orow[tid+512]=y2;
  }
  if(outb){
    __hip_bfloat16* orow = outb + (size_t)row*C_;
    orow[tid]=__float2bfloat16(y0); orow[tid+256]=__float2bfloat16(y1); orow[tid+512]=__float2bfloat16(y2);
  }
}

// ---------------- Wm[c][d] = mean over heads of w_qkv k-columns (for metric) ----------------
__global__ __launch_bounds__(256) void wmean_kernel(const float* __restrict__ w,
    float* __restrict__ Wm){
  int t = blockIdx.x*256 + threadIdx.x;   // t = c*64+d
  if(t >= C_*64) return;
  int c = t>>6, d = t&63;
  const float* p = w + (size_t)c*(3*C_) + C_ + d;
  float s=0.f;
#pragma unroll
  for(int h=0;h<H_;h++) s += p[h*64];
  Wm[t] = s*(1.0f/12.0f);
}

// ---------------- transpose f32 [K,N] -> bf16 [N,K] ----------------
__global__ __launch_bounds__(256) void transpose_bf16(const float* __restrict__ w,
    __hip_bfloat16* __restrict__ wt, int K, int N){
  __shared__ float tile[32][33];
  int n0 = blockIdx.x*32, k0 = blockIdx.y*32;
  int tx = threadIdx.x&31, ty = threadIdx.x>>5;
  for(int r=ty;r<32;r+=8) tile[r][tx] = w[(size_t)(k0+r)*N + n0+tx];
  __syncthreads();
  for(int r=ty;r<32;r+=8) wt[(size_t)(n0+r)*K + k0+tx] = __float2bfloat16(tile[tx][r]);
}

// ---------------- bf16 MFMA GEMM: C = A[MxK] @ Bt[NxK]^T, f32 accum ----------------
// EPI: 1/3 = (res+v)+bias -> f32; 2 = v+bias, exact GELU -> bf16; 4 = store bf16
template<int EPI>
__global__ __launch_bounds__(256) void gemm_bf16(const ushort* __restrict__ A,
    const ushort* __restrict__ Bt, const float* __restrict__ bias,
    const float* __restrict__ res, void* __restrict__ Cout,
    int M, int N, int K){
  constexpr int BM=128, BN=128, BK=32;
  __shared__ ushort As[BM][40];
  __shared__ ushort Bs[BN][40];
  int tid = threadIdx.x;
  int bm = blockIdx.y*BM, bn = blockIdx.x*BN;
  int w = tid>>6, l = tid&63;
  int wm = (w>>1)*64, wn = (w&1)*64;
  int lr = l&15, lc = l>>4;           // frag row/col, k-chunk
  f32x4 acc[4][4] = {};
  for(int k0=0;k0<K;k0+=BK){
#pragma unroll
    for(int s=0;s<2;s++){
      int cid = tid + s*256;          // 512 chunks: row=cid>>2, ch=cid&3
      int r = cid>>2, ch = cid&3;
      int4v va = {0,0,0,0};
      if(bm+r < M) va = *reinterpret_cast<const int4v*>(A + (size_t)(bm+r)*K + k0 + ch*8);
      *reinterpret_cast<int4v*>(&As[r][ch*8]) = va;
      int4v vb = *reinterpret_cast<const int4v*>(Bt + (size_t)(bn+r)*K + k0 + ch*8);
      *reinterpret_cast<int4v*>(&Bs[r][ch*8]) = vb;
    }
    __syncthreads();
    short8v af[4], bfr[4];
#pragma unroll
    for(int f=0; f<4; f++){
      af[f]  = *reinterpret_cast<const short8v*>(&As[wm + f*16 + lr][lc*8]);
      bfr[f] = *reinterpret_cast<const short8v*>(&Bs[wn + f*16 + lr][lc*8]);
    }
#pragma unroll
    for(int i=0;i<4;i++)
#pragma unroll
      for(int j=0;j<4;j++)
        acc[i][j] = __builtin_amdgcn_mfma_f32_16x16x32_bf16(af[i], bfr[j], acc[i][j], 0,0,0);
    __syncthreads();
  }
#pragma unroll
  for(int i=0;i<4;i++){
    int rbase = bm + wm + i*16 + lc*4;
#pragma unroll
    for(int j=0;j<4;j++){
      int col = bn + wn + j*16 + lr;
#pragma unroll
      for(int r=0;r<4;r++){
        int row = rbase + r;
        if(row >= M) continue;
        size_t idx = (size_t)row*N + col;
        float v = acc[i][j][r];
        if constexpr(EPI==1 || EPI==3) ((float*)Cout)[idx] = (res[idx] + v) + bias[col];
        if constexpr(EPI==2){
          v += bias[col];
          v = 0.5f*v*(1.0f+erff(v*0.70710678118654752f));
          ((__hip_bfloat16*)Cout)[idx] = __float2bfloat16(v);
        }
        if constexpr(EPI==4) ((__hip_bfloat16*)Cout)[idx] = __float2bfloat16(v);
      }
    }
  }
}

// ---------------- metric = h @ Wm (f32, sequential k), normalize, drop cls ----------------
__global__ __launch_bounds__(64) void metric_gemm(const float* __restrict__ h,
    const float* __restrict__ Wm, float* __restrict__ mnorm){
  int row = blockIdx.x;
  int b = row / N_, n = row - b*N_;
  __shared__ float hs[C_];
  int l = threadIdx.x;
  for(int c=l;c<C_;c+=64) hs[c]=h[(size_t)row*C_+c];
  __syncthreads();
  float acc=0.f;
#pragma unroll 4
  for(int c=0;c<C_;c++) acc = fmaf(hs[c], Wm[c*64+l], acc);
  float q=acc*acc;
#pragma unroll
  for(int o=32;o;o>>=1) q += __shfl_xor(q,o);
  float nrm = sqrtf(q);
  if(n>=1) mnorm[((size_t)b*T_+(n-1))*64+l] = acc/nrm;
}

// ---------------- MFMA attention: one block per (b,h), 4 waves, q-tiles of 16 ----------------
__global__ __launch_bounds__(256) void attn_mfma(const ushort* __restrict__ qkv,
    const float* __restrict__ attn_size, __hip_bfloat16* __restrict__ xa){
  int h = blockIdx.x, b = blockIdx.y;
  __shared__ ushort Ks[208][72];
  __shared__ ushort VsT[64][232];
  __shared__ ushort Ps[4][16][232];
  __shared__ float lsz[208];
  int tid = threadIdx.x;
  int w = tid>>6, l = tid&63;
  int lr = l&15, lc = l>>4;
  const size_t QROW = 3*C_;
  for(int t=tid; t<208*64; t+=256){
    int n=t>>6, d=t&63;
    ushort v = 0;
    if(n<197) v = qkv[((size_t)(b*N_+n))*QROW + C_ + h*64 + d];
    Ks[n][d] = v;
  }
  for(int t=tid; t<232*64; t+=256){
    int n=t>>6, d=t&63;
    ushort v = 0;
    if(n<197) v = qkv[((size_t)(b*N_+n))*QROW + 2*C_ + h*64 + d];
    VsT[d][n] = v;
  }
  for(int t=tid;t<208;t+=256) lsz[t] = (t<197)? logf(attn_size[b*N_+t]) : 0.f;
  for(int c=l; c<16*24; c+=64){ int rr=c/24, cc=208+(c%24); Ps[w][rr][cc]=0; }
  __syncthreads();

  for(int qt=w; qt<13; qt+=4){
    int qrow = min(qt*16 + lr, 196);
    const ushort* qp = qkv + ((size_t)(b*N_+qrow))*QROW + h*64;
    short8v aq0 = *reinterpret_cast<const short8v*>(qp + lc*8);
    short8v aq1 = *reinterpret_cast<const short8v*>(qp + 32 + lc*8);
    float sc[13][4];
#pragma unroll
    for(int t=0;t<13;t++){
      short8v b0 = *reinterpret_cast<const short8v*>(&Ks[t*16+lr][lc*8]);
      short8v b1 = *reinterpret_cast<const short8v*>(&Ks[t*16+lr][32+lc*8]);
      f32x4 a = {0.f,0.f,0.f,0.f};
      a = __builtin_amdgcn_mfma_f32_16x16x32_bf16(aq0, b0, a, 0,0,0);
      a = __builtin_amdgcn_mfma_f32_16x16x32_bf16(aq1, b1, a, 0,0,0);
      float ls = lsz[t*16+lr];
      bool mask = (t==12) && (lr>=5);
#pragma unroll
      for(int r=0;r<4;r++) sc[t][r] = mask ? -1e30f : (a[r]*0.125f + ls);
    }
    float rsum[4];
#pragma unroll
    for(int r=0;r<4;r++){
      float m=-1e30f;
#pragma unroll
      for(int t=0;t<13;t++) m = fmaxf(m, sc[t][r]);
#pragma unroll
      for(int o=1;o<16;o<<=1) m = fmaxf(m, __shfl_xor(m,o));
      float s=0.f;
#pragma unroll
      for(int t=0;t<13;t++){ float p=expf(sc[t][r]-m); sc[t][r]=p; s+=p; }
#pragma unroll
      for(int o=1;o<16;o<<=1) s += __shfl_xor(s,o);
      rsum[r]=s;
    }
#pragma unroll
    for(int t=0;t<13;t++)
#pragma unroll
      for(int r=0;r<4;r++)
        Ps[w][lc*4+r][t*16+lr] = f2bf(sc[t][r]);
    LGKM0();
    short8v ap[7];
#pragma unroll
    for(int ks=0;ks<7;ks++) ap[ks] = *reinterpret_cast<const short8v*>(&Ps[w][lr][ks*32 + lc*8]);
#pragma unroll
    for(int f=0; f<4; f++){
      f32x4 o = {0.f,0.f,0.f,0.f};
#pragma unroll
      for(int ks=0;ks<7;ks++){
        short8v bv = *reinterpret_cast<const short8v*>(&VsT[f*16+lr][ks*32 + lc*8]);
        o = __builtin_amdgcn_mfma_f32_16x16x32_bf16(ap[ks], bv, o, 0,0,0);
      }
#pragma unroll
      for(int r=0;r<4;r++){
        int q = qt*16 + lc*4 + r;
        if(q<197) xa[((size_t)(b*N_+q))*C_ + h*64 + f*16 + lr] = __float2bfloat16(o[r]/rsum[r]);
      }
    }
  }
}

// ---------------- agglomerative clustering: round-5 logic, 3 barriers/iter ----------------
// Structural change only vs the verified round-5 kernel: each of the 4 waves computes the
// global argmin REDUNDANTLY (4 strided rowmin reads + shfl_xor butterfly, identical
// lexicographic (rowmin,row) result as the old tid0 funnel), and reads rowarg[i]/sizes
// directly (wave-uniform LDS broadcasts). Phase C/D and E bodies are VERBATIM round 5.
// Barrier proof: A reads rowmin/rowarg/sizes (written last in prior C/D/E -> barrier3);
// C/D reads D/rowmin/labels/active before writing only thread-owned cells -- every
// cross-thread overlapping cell is either discarded (k in {i,j} -> kact false) or written
// with the identical value (D[i][j]=D[j][i]=INF by both writers); E reads D/rlist (b2)
// and writes rowmin (b3 before next A).
__global__ __launch_bounds__(256) void cluster_kernel(const float* __restrict__ mnorm,
    int* __restrict__ labs_ws, float* __restrict__ labs_out){
  int b = blockIdx.x;
  __shared__ float D[T_][T_+1];
  __shared__ float sizes[T_];
  __shared__ int   labels[T_];
  __shared__ int   active[T_];
  __shared__ float rowmin[T_];
  __shared__ int   rowarg[T_];
  __shared__ int   rlist[T_];
  __shared__ int   rcnt;
  int tid = threadIdx.x;
  int w = tid>>6, l = tid&63;
  const float* mb = mnorm + (size_t)b*T_*64;

  for(int t=tid;t<T_*T_;t+=256){
    int r=t/T_, c=t%T_;
    float dot=0.0f;
    for(int d=0;d<64;d++) dot += mb[r*64+d]*mb[c*64+d];
    D[r][c] = (r==c) ? INF_ : (1.0f - dot);
  }
  for(int t=tid;t<T_;t+=256){ sizes[t]=1.0f; labels[t]=t; active[t]=1; }
  __syncthreads();
  if(tid<T_){                    // init row minima (strict < -> first col)
    float bvv=INF_; int ba=0;
    for(int c=0;c<T_;c++){ float v=D[tid][c]; if(v<bvv){ bvv=v; ba=c; } }
    rowmin[tid]=bvv; rowarg[tid]=ba;
  }
  __syncthreads();

  for(int it=0; it<T_-KC_; it++){
    // --- phase A: global argmin over (rowmin[r], r), redundant per wave ---
    float bv=INF_; int bi=0x7fffffff;
#pragma unroll
    for(int s=0;s<4;s++){
      int k=s*64+l;
      float v = (k<T_) ? rowmin[k] : INF_;
      if(v<bv){ bv=v; bi=k; }         // ascending k -> first index on ties
    }
#pragma unroll
    for(int o=32;o;o>>=1){
      float ov=__shfl_xor(bv,o); int oi=__shfl_xor(bi,o);
      if(ov<bv || (ov==bv && oi<bi)){ bv=ov; bi=oi; }
    }
    int i = bi;
    int j = rowarg[i];                 // wave-uniform broadcast reads
    float ni = sizes[i], nj = sizes[j];
    if(tid==0) rcnt = 0;
    __syncthreads();                   // b1: A-reads done before C/D writes
    // --- phase C/D: Lance-Williams update + incremental rowmin (verbatim round 5) ---
    int k=tid;
    if(k<T_){
      float di=D[i][k], dj=D[j][k];
      float oldrm=rowmin[k]; int oldarg=rowarg[k];
      bool kact = (k!=i) && (k!=j) && (active[k]!=0);
      float nd = kact ? (ni*di + nj*dj) / (ni+nj) : INF_;
      D[i][k]=nd; D[k][i]=nd; D[j][k]=INF_; D[k][j]=INF_;
      if(labels[k]==j) labels[k]=i;
      if(k==i){
        int p=atomicAdd(&rcnt,1); rlist[p]=k;                 // row i: full rescan
      } else if(k==j){
        rowmin[k]=INF_; rowarg[k]=0;
      } else if(kact){
        if(oldarg==i){
          if(nd<=oldrm) rowmin[k]=nd;
          else { int p=atomicAdd(&rcnt,1); rlist[p]=k; }
        } else if(oldarg==j){
          if(nd<=oldrm){ rowmin[k]=nd; rowarg[k]=i; }
          else { int p=atomicAdd(&rcnt,1); rlist[p]=k; }
        } else {
          if(nd<oldrm || (nd==oldrm && i<oldarg)){ rowmin[k]=nd; rowarg[k]=i; }
        }
      }
    }
    if(tid==0){ sizes[i]=ni+nj; active[j]=0; }
    __syncthreads();                   // b2: D/rlist writes visible for rescans
    // --- phase E: full rescans (one wave per flagged row; verbatim round 5) ---
    int nr = rcnt;
    for(int q=w; q<nr; q+=4){
      int rr = rlist[q];
      float v=INF_; int c=0x7fffffff;
      for(int cc=l; cc<T_; cc+=64){
        float vv=D[rr][cc];
        if(vv<v){ v=vv; c=cc; }
      }
#pragma unroll
      for(int o=32;o;o>>=1){
        float ov=__shfl_xor(v,o); int oc=__shfl_xor(c,o);
        if(ov<v || (ov==v && oc<c)){ v=ov; c=oc; }
      }
      if(l==0){ rowmin[rr]=v; rowarg[rr]=c; }
    }
    __syncthreads();                   // b3: rowmin/rowarg visible for next A
  }

  if(tid==0){
    int c=0;
    for(int t=0;t<T_;t++){ c += active[t]; rlist[t]=c-1; }    // rlist = rank now
    labs_ws[b*N_]=0; labs_out[b*N_]=0.0f;
  }
  __syncthreads();
  for(int t=tid;t<T_;t+=256){
    int lab = rlist[labels[t]] + 1;
    labs_ws[b*N_+1+t] = lab;
    labs_out[b*N_+1+t] = (float)lab;
  }
}

// ---------------- weighted-average merge: one block per (chunk of 256 ch, b) ----------------
__global__ __launch_bounds__(256) void merge_kernel(const float* __restrict__ x1,
    const float* __restrict__ asz, const int* __restrict__ labs,
    float* __restrict__ x2, float* __restrict__ size_out){
  int chunk = blockIdx.x;     // 0..2 (C_/256)
  int b = blockIdx.y;
  __shared__ float acc[KT_][256];
  __shared__ int   lab[N_];
  __shared__ float sz[N_];
  __shared__ float ssum[KT_];
  int tid = threadIdx.x;
  for(int t=tid;t<N_;t+=256){ lab[t]=labs[b*N_+t]; sz[t]=asz[b*N_+t]; }
#pragma unroll
  for(int k=0;k<KT_;k++) acc[k][tid]=0.f;
  __syncthreads();
  if(tid<KT_){
    float s=0.f;
    for(int n=0;n<N_;n++) if(lab[n]==tid) s += sz[n];
    ssum[tid]=s;
  }
  int c = chunk*256 + tid;
  const float* xb = x1 + (size_t)b*N_*C_ + c;
  for(int n=0;n<N_;n++){
    float v = xb[(size_t)n*C_];
    int k = lab[n];
    acc[k][tid] += v * sz[n];
  }
  __syncthreads();
  for(int k=0;k<KT_;k++)
    x2[((size_t)(b*KT_+k))*C_ + c] = acc[k][tid] / ssum[k];
  if(chunk==0 && tid<KT_) size_out[b*KT_+tid] = ssum[tid];
}

extern "C" void kernel_launch(void* const* d_in, const int* in_sizes, int n_in,
                              void* d_out, int out_size, void* d_ws, size_t ws_size,
                              hipStream_t stream){
  const float* x      = (const float*)d_in[0];
  const float* asz    = (const float*)d_in[1];
  const float* n1_g   = (const float*)d_in[2];
  const float* n1_b   = (const float*)d_in[3];
  const float* w_qkv  = (const float*)d_in[4];
  const float* w_proj = (const float*)d_in[5];
  const float* b_proj = (const float*)d_in[6];
  const float* n2_g   = (const float*)d_in[7];
  const float* n2_b   = (const float*)d_in[8];
  const float* w_fc1  = (const float*)d_in[9];
  const float* b_fc1  = (const float*)d_in[10];
  const float* w_fc2  = (const float*)d_in[11];
  const float* b_fc2  = (const float*)d_in[12];

  const size_t ROWS = (size_t)B_*N_;        // 12608
  const size_t M2   = (size_t)B_*KT_;       // 6336
  float* ws = (float*)d_ws;

  float* h     = ws;                                    // [ROWS*C] f32 LN1 out; later x1
  float* qkvR  = h + ROWS*C_;                           // region, ROWS*3C floats
  __hip_bfloat16* qkvb = (__hip_bfloat16*)qkvR;         // qkv as bf16 (attn-only consumer)
  float* x2    = qkvR;                                  // [M2*C] alias (qkv dead by merge)
  __hip_bfloat16* h2b = (__hip_bfloat16*)(qkvR + M2*C_);
  __hip_bfloat16* h3b = (__hip_bfloat16*)(qkvR + M2*C_ + M2*C_/2);
  __hip_bfloat16* hb  = (__hip_bfloat16*)(qkvR + ROWS*3*C_);      // [ROWS*C] bf16; later xa
  __hip_bfloat16* xa  = hb;
  float* mnorm = (float*)(hb) + ROWS*C_/2;
  float* Wm    = mnorm + (size_t)B_*T_*64;
  __hip_bfloat16* wqkvT = (__hip_bfloat16*)(Wm + C_*64);
  __hip_bfloat16* wprojT= (__hip_bfloat16*)((float*)wqkvT + (size_t)3*C_*C_/2);
  __hip_bfloat16* wfc1T = (__hip_bfloat16*)((float*)wprojT + (size_t)C_*C_/2);
  __hip_bfloat16* wfc2T = (__hip_bfloat16*)((float*)wfc1T + (size_t)C_*HF_/2);
  int*   labs  = (int*)((float*)wfc2T + (size_t)HF_*C_/2);
  float* x1    = h;

  float* out     = (float*)d_out;
  float* out_sz  = out + M2*C_;
  float* out_lab = out_sz + M2;

  // prep
  ln_kernel<<<dim3((unsigned)ROWS),256,0,stream>>>(x, n1_g, n1_b, h, hb);
  wmean_kernel<<<dim3(192),256,0,stream>>>(w_qkv, Wm);
  transpose_bf16<<<dim3(72,24),256,0,stream>>>(w_qkv, wqkvT, C_, 3*C_);
  transpose_bf16<<<dim3(24,24),256,0,stream>>>(w_proj, wprojT, C_, C_);
  transpose_bf16<<<dim3(96,24),256,0,stream>>>(w_fc1, wfc1T, C_, HF_);
  transpose_bf16<<<dim3(24,96),256,0,stream>>>(w_fc2, wfc2T, HF_, C_);

  // attention block
  gemm_bf16<4><<<dim3(18,99),256,0,stream>>>((const ushort*)hb, (const ushort*)wqkvT,
      nullptr, nullptr, qkvb, (int)ROWS, 3*C_, C_);
  metric_gemm<<<dim3((unsigned)ROWS),64,0,stream>>>(h, Wm, mnorm);
  attn_mfma<<<dim3(H_,B_),256,0,stream>>>((const ushort*)qkvb, asz, xa);
  gemm_bf16<1><<<dim3(6,99),256,0,stream>>>((const ushort*)xa, (const ushort*)wprojT,
      b_proj, x, x1, (int)ROWS, C_, C_);

  // clustering + merge
  cluster_kernel<<<dim3(B_),256,0,stream>>>(mnorm, labs, out_lab);
  merge_kernel<<<dim3(3,B_),256,0,stream>>>(x1, asz, labs, x2, out_sz);

  // MLP
  ln_kernel<<<dim3((unsigned)M2),256,0,stream>>>(x2, n2_g, n2_b, nullptr, h2b);
  gemm_bf16<2><<<dim3(24,50),256,0,stream>>>((const ushort*)h2b, (const ushort*)wfc1T,
      b_fc1, nullptr, h3b, (int)M2, HF_, C_);
  gemm_bf16<3><<<dim3(6,50),256,0,stream>>>((const ushort*)h3b, (const ushort*)wfc2T,
      b_fc2, x2, out, (int)M2, C_, HF_);
}

// Round 9
// 1157.796 us; speedup vs baseline: 1.2916x; 1.0524x over previous
//
#include <hip/hip_runtime.h>
#include <hip/hip_bf16.h>
#include <math.h>

#define INF_ 1e10f
#define LGKM0() asm volatile("s_waitcnt lgkmcnt(0)" ::: "memory")

static constexpr int B_  = 64;
static constexpr int N_  = 197;
static constexpr int C_  = 768;
static constexpr int H_  = 12;
static constexpr int T_  = 196;   // N-1 tokens clustered
static constexpr int KC_ = 98;    // NUM_CLUSTERS
static constexpr int KT_ = 99;    // NUM_CLUSTERS + 1
static constexpr int HF_ = 3072;

typedef __attribute__((ext_vector_type(8))) short short8v;
typedef __attribute__((ext_vector_type(4))) float f32x4;
typedef __attribute__((ext_vector_type(4))) int int4v;

__device__ __forceinline__ float wave_sum(float v){
#pragma unroll
  for(int o=32;o;o>>=1) v += __shfl_down(v,o);
  return v;
}

__device__ __forceinline__ ushort f2bf(float v){
  __hip_bfloat16 t = __float2bfloat16(v);
  return *reinterpret_cast<const ushort*>(&t);
}

// Monotone float->u32 (total order matches float <, all finite values; -0/+0 differ but
// -0.0 provably never occurs in this kernel's distance values).
__device__ __forceinline__ unsigned long long packkey(float v, int r, int a){
  unsigned int bb = __float_as_uint(v);
  bb ^= (bb & 0x80000000u) ? 0xFFFFFFFFu : 0x80000000u;
  return ((unsigned long long)bb<<32) | (unsigned)(r<<8) | (unsigned)a;
}
__device__ __forceinline__ float unpackval(unsigned long long key){
  unsigned u = (unsigned)(key>>32);
  u = (u & 0x80000000u) ? (u ^ 0x80000000u) : ~u;
  return __uint_as_float(u);
}

// ---------------- LayerNorm (row = 768, block = 256); writes f32 and/or bf16 ----------------
__global__ __launch_bounds__(256) void ln_kernel(const float* __restrict__ in,
    const float* __restrict__ g, const float* __restrict__ bb,
    float* __restrict__ outf, __hip_bfloat16* __restrict__ outb){
  int row = blockIdx.x;
  const float* xr = in + (size_t)row*C_;
  int tid = threadIdx.x;
  float v0=xr[tid], v1=xr[tid+256], v2=xr[tid+512];
  __shared__ float sred[4];
  __shared__ float smean, svar;
  float s = wave_sum(v0+v1+v2);
  int w=tid>>6, l=tid&63;
  if(l==0) sred[w]=s;
  __syncthreads();
  if(tid==0) smean = (sred[0]+sred[1]+sred[2]+sred[3])/(float)C_;
  __syncthreads();
  float m = smean;
  float d0=v0-m, d1=v1-m, d2=v2-m;
  float q = wave_sum(d0*d0+d1*d1+d2*d2);
  if(l==0) sred[w]=q;
  __syncthreads();
  if(tid==0) svar = (sred[0]+sred[1]+sred[2]+sred[3])/(float)C_;
  __syncthreads();
  float sq = sqrtf(svar + 1e-5f);
  float y0 = d0/sq*g[tid]     + bb[tid];
  float y1 = d1/sq*g[tid+256] + bb[tid+256];
  float y2 = d2/sq*g[tid+512] + bb[tid+512];
  if(outf){
    float* orow = outf + (size_t)row*C_;
    orow[tid]=y0; orow[tid+256]=y1; orow[tid+512]=y2;
  }
  if(outb){
    __hip_bfloat16* orow = outb + (size_t)row*C_;
    orow[tid]=__float2bfloat16(y0); orow[tid+256]=__float2bfloat16(y1); orow[tid+512]=__float2bfloat16(y2);
  }
}

// ---------------- Wm[c][d] = mean over heads of w_qkv k-columns (for metric) ----------------
__global__ __launch_bounds__(256) void wmean_kernel(const float* __restrict__ w,
    float* __restrict__ Wm){
  int t = blockIdx.x*256 + threadIdx.x;   // t = c*64+d
  if(t >= C_*64) return;
  int c = t>>6, d = t&63;
  const float* p = w + (size_t)c*(3*C_) + C_ + d;
  float s=0.f;
#pragma unroll
  for(int h=0;h<H_;h++) s += p[h*64];
  Wm[t] = s*(1.0f/12.0f);
}

// ---------------- transpose f32 [K,N] -> bf16 [N,K] ----------------
__global__ __launch_bounds__(256) void transpose_bf16(const float* __restrict__ w,
    __hip_bfloat16* __restrict__ wt, int K, int N){
  __shared__ float tile[32][33];
  int n0 = blockIdx.x*32, k0 = blockIdx.y*32;
  int tx = threadIdx.x&31, ty = threadIdx.x>>5;
  for(int r=ty;r<32;r+=8) tile[r][tx] = w[(size_t)(k0+r)*N + n0+tx];
  __syncthreads();
  for(int r=ty;r<32;r+=8) wt[(size_t)(n0+r)*K + k0+tx] = __float2bfloat16(tile[tx][r]);
}

// ---------------- bf16 MFMA GEMM: C = A[MxK] @ Bt[NxK]^T, f32 accum ----------------
// EPI: 1/3 = (res+v)+bias -> f32; 2 = v+bias, exact GELU -> bf16; 4 = store bf16
template<int EPI>
__global__ __launch_bounds__(256) void gemm_bf16(const ushort* __restrict__ A,
    const ushort* __restrict__ Bt, const float* __restrict__ bias,
    const float* __restrict__ res, void* __restrict__ Cout,
    int M, int N, int K){
  constexpr int BM=128, BN=128, BK=32;
  __shared__ ushort As[BM][40];
  __shared__ ushort Bs[BN][40];
  int tid = threadIdx.x;
  int bm = blockIdx.y*BM, bn = blockIdx.x*BN;
  int w = tid>>6, l = tid&63;
  int wm = (w>>1)*64, wn = (w&1)*64;
  int lr = l&15, lc = l>>4;           // frag row/col, k-chunk
  f32x4 acc[4][4] = {};
  for(int k0=0;k0<K;k0+=BK){
#pragma unroll
    for(int s=0;s<2;s++){
      int cid = tid + s*256;          // 512 chunks: row=cid>>2, ch=cid&3
      int r = cid>>2, ch = cid&3;
      int4v va = {0,0,0,0};
      if(bm+r < M) va = *reinterpret_cast<const int4v*>(A + (size_t)(bm+r)*K + k0 + ch*8);
      *reinterpret_cast<int4v*>(&As[r][ch*8]) = va;
      int4v vb = *reinterpret_cast<const int4v*>(Bt + (size_t)(bn+r)*K + k0 + ch*8);
      *reinterpret_cast<int4v*>(&Bs[r][ch*8]) = vb;
    }
    __syncthreads();
    short8v af[4], bfr[4];
#pragma unroll
    for(int f=0; f<4; f++){
      af[f]  = *reinterpret_cast<const short8v*>(&As[wm + f*16 + lr][lc*8]);
      bfr[f] = *reinterpret_cast<const short8v*>(&Bs[wn + f*16 + lr][lc*8]);
    }
#pragma unroll
    for(int i=0;i<4;i++)
#pragma unroll
      for(int j=0;j<4;j++)
        acc[i][j] = __builtin_amdgcn_mfma_f32_16x16x32_bf16(af[i], bfr[j], acc[i][j], 0,0,0);
    __syncthreads();
  }
#pragma unroll
  for(int i=0;i<4;i++){
    int rbase = bm + wm + i*16 + lc*4;
#pragma unroll
    for(int j=0;j<4;j++){
      int col = bn + wn + j*16 + lr;
#pragma unroll
      for(int r=0;r<4;r++){
        int row = rbase + r;
        if(row >= M) continue;
        size_t idx = (size_t)row*N + col;
        float v = acc[i][j][r];
        if constexpr(EPI==1 || EPI==3) ((float*)Cout)[idx] = (res[idx] + v) + bias[col];
        if constexpr(EPI==2){
          v += bias[col];
          v = 0.5f*v*(1.0f+erff(v*0.70710678118654752f));
          ((__hip_bfloat16*)Cout)[idx] = __float2bfloat16(v);
        }
        if constexpr(EPI==4) ((__hip_bfloat16*)Cout)[idx] = __float2bfloat16(v);
      }
    }
  }
}

// ---------------- metric = h @ Wm (f32, sequential k), normalize, drop cls ----------------
// 16 rows per block (4 waves x 4 rows); Wm read once per wave per c (amortized 4x),
// per-row accumulation order identical to the verified single-row version.
__global__ __launch_bounds__(256) void metric_gemm(const float* __restrict__ h,
    const float* __restrict__ Wm, float* __restrict__ mnorm){
  int row0 = blockIdx.x*16;
  __shared__ float hs[16][C_];
  int tid = threadIdx.x;
  int w = tid>>6, l = tid&63;
  for(int t=tid; t<16*C_; t+=256)
    hs[t/C_][t%C_] = h[(size_t)row0*C_ + t];
  __syncthreads();
  float a0=0.f,a1=0.f,a2=0.f,a3=0.f;
#pragma unroll 4
  for(int c=0;c<C_;c++){
    float wv = Wm[c*64+l];
    a0 = fmaf(hs[w*4+0][c], wv, a0);
    a1 = fmaf(hs[w*4+1][c], wv, a1);
    a2 = fmaf(hs[w*4+2][c], wv, a2);
    a3 = fmaf(hs[w*4+3][c], wv, a3);
  }
  float accs[4] = {a0,a1,a2,a3};
#pragma unroll
  for(int r=0;r<4;r++){
    float acc = accs[r];
    float q = acc*acc;
#pragma unroll
    for(int o=32;o;o>>=1) q += __shfl_xor(q,o);
    float nrm = sqrtf(q);
    int row = row0 + w*4 + r;
    int bb = row / N_, n = row - bb*N_;
    if(n>=1) mnorm[((size_t)bb*T_+(n-1))*64+l] = acc/nrm;
  }
}

// ---------------- MFMA attention: one block per (b,h), 4 waves, q-tiles of 16 ----------------
__global__ __launch_bounds__(256) void attn_mfma(const ushort* __restrict__ qkv,
    const float* __restrict__ attn_size, __hip_bfloat16* __restrict__ xa){
  int h = blockIdx.x, b = blockIdx.y;
  __shared__ ushort Ks[208][72];
  __shared__ ushort VsT[64][232];
  __shared__ ushort Ps[4][16][232];
  __shared__ float lsz[208];
  int tid = threadIdx.x;
  int w = tid>>6, l = tid&63;
  int lr = l&15, lc = l>>4;
  const size_t QROW = 3*C_;
  for(int t=tid; t<208*64; t+=256){
    int n=t>>6, d=t&63;
    ushort v = 0;
    if(n<197) v = qkv[((size_t)(b*N_+n))*QROW + C_ + h*64 + d];
    Ks[n][d] = v;
  }
  for(int t=tid; t<232*64; t+=256){
    int n=t>>6, d=t&63;
    ushort v = 0;
    if(n<197) v = qkv[((size_t)(b*N_+n))*QROW + 2*C_ + h*64 + d];
    VsT[d][n] = v;
  }
  for(int t=tid;t<208;t+=256) lsz[t] = (t<197)? logf(attn_size[b*N_+t]) : 0.f;
  for(int c=l; c<16*24; c+=64){ int rr=c/24, cc=208+(c%24); Ps[w][rr][cc]=0; }
  __syncthreads();

  for(int qt=w; qt<13; qt+=4){
    int qrow = min(qt*16 + lr, 196);
    const ushort* qp = qkv + ((size_t)(b*N_+qrow))*QROW + h*64;
    short8v aq0 = *reinterpret_cast<const short8v*>(qp + lc*8);
    short8v aq1 = *reinterpret_cast<const short8v*>(qp + 32 + lc*8);
    float sc[13][4];
#pragma unroll
    for(int t=0;t<13;t++){
      short8v b0 = *reinterpret_cast<const short8v*>(&Ks[t*16+lr][lc*8]);
      short8v b1 = *reinterpret_cast<const short8v*>(&Ks[t*16+lr][32+lc*8]);
      f32x4 a = {0.f,0.f,0.f,0.f};
      a = __builtin_amdgcn_mfma_f32_16x16x32_bf16(aq0, b0, a, 0,0,0);
      a = __builtin_amdgcn_mfma_f32_16x16x32_bf16(aq1, b1, a, 0,0,0);
      float ls = lsz[t*16+lr];
      bool mask = (t==12) && (lr>=5);
#pragma unroll
      for(int r=0;r<4;r++) sc[t][r] = mask ? -1e30f : (a[r]*0.125f + ls);
    }
    float rsum[4];
#pragma unroll
    for(int r=0;r<4;r++){
      float m=-1e30f;
#pragma unroll
      for(int t=0;t<13;t++) m = fmaxf(m, sc[t][r]);
#pragma unroll
      for(int o=1;o<16;o<<=1) m = fmaxf(m, __shfl_xor(m,o));
      float s=0.f;
#pragma unroll
      for(int t=0;t<13;t++){ float p=expf(sc[t][r]-m); sc[t][r]=p; s+=p; }
#pragma unroll
      for(int o=1;o<16;o<<=1) s += __shfl_xor(s,o);
      rsum[r]=s;
    }
#pragma unroll
    for(int t=0;t<13;t++)
#pragma unroll
      for(int r=0;r<4;r++)
        Ps[w][lc*4+r][t*16+lr] = f2bf(sc[t][r]);
    LGKM0();
    short8v ap[7];
#pragma unroll
    for(int ks=0;ks<7;ks++) ap[ks] = *reinterpret_cast<const short8v*>(&Ps[w][lr][ks*32 + lc*8]);
#pragma unroll
    for(int f=0; f<4; f++){
      f32x4 o = {0.f,0.f,0.f,0.f};
#pragma unroll
      for(int ks=0;ks<7;ks++){
        short8v bv = *reinterpret_cast<const short8v*>(&VsT[f*16+lr][ks*32 + lc*8]);
        o = __builtin_amdgcn_mfma_f32_16x16x32_bf16(ap[ks], bv, o, 0,0,0);
      }
#pragma unroll
      for(int r=0;r<4;r++){
        int q = qt*16 + lc*4 + r;
        if(q<197) xa[((size_t)(b*N_+q))*C_ + h*64 + f*16 + lr] = __float2bfloat16(o[r]/rsum[r]);
      }
    }
  }
}

// ---------------- agglomerative clustering: packed-u64-key + LDS atomicMin ----------------
// rowkey[r] = (monotone(rowmin) << 32) | (r << 8) | rowarg.  Key compare == lexicographic
// (rowmin, r, arg); rows are unique so (rowmin, r) ties never fall through to arg ->
// phase-A winner identical to round 8's (rowmin, r) argmin, and j comes free from the
// winning key's arg bits. C/D update compares/formulas are VERBATIM round 8 on unpacked
// floats. Phase E rescan: per fixed row rr, key compare == (value, cc) -> first-col
// tie-break, same as round 8. 3 barriers/iter, same ordering proof as round 8.
__global__ __launch_bounds__(256) void cluster_kernel(const float* __restrict__ mnorm,
    int* __restrict__ labs_ws, float* __restrict__ labs_out){
  int b = blockIdx.x;
  __shared__ unsigned long long rowkey[T_];
  __shared__ unsigned long long gkey[2][4];   // [parity][wave]
  __shared__ unsigned long long scratch[4];   // per-wave rescan scratch
  __shared__ float D[T_][T_+1];
  __shared__ float sizes[T_];
  __shared__ int   labels[T_];
  __shared__ int   active[T_];
  __shared__ int   rlist[T_];
  __shared__ int   rcnt;
  int tid = threadIdx.x;
  int w = tid>>6, l = tid&63;
  const float* mb = mnorm + (size_t)b*T_*64;

  for(int t=tid;t<T_*T_;t+=256){
    int r=t/T_, c=t%T_;
    float dot=0.0f;
    for(int d=0;d<64;d++) dot += mb[r*64+d]*mb[c*64+d];
    D[r][c] = (r==c) ? INF_ : (1.0f - dot);
  }
  for(int t=tid;t<T_;t+=256){ sizes[t]=1.0f; labels[t]=t; active[t]=1; }
  if(tid<8) gkey[tid>>2][tid&3] = ~0ULL;
  __syncthreads();
  if(tid<T_){                    // init row minima (strict < -> first col)
    float bvv=INF_; int ba=0;
    for(int c=0;c<T_;c++){ float v=D[tid][c]; if(v<bvv){ bvv=v; ba=c; } }
    rowkey[tid] = packkey(bvv, tid, ba);
  }
  __syncthreads();

  for(int it=0; it<T_-KC_; it++){
    int p = it&1;
    // --- phase A: global argmin via per-wave u64 atomicMin ---
    unsigned long long key = (tid<T_) ? rowkey[tid] : ~0ULL;
    atomicMin(&gkey[p][w], key);
    if(tid==0) rcnt = 0;
    __syncthreads();                   // b1: atomics done; A-reads before C/D writes
    unsigned long long g0=gkey[p][0], g1=gkey[p][1];
    unsigned long long g2=gkey[p][2], g3=gkey[p][3];
    unsigned long long ga = g0<g1?g0:g1, gb2 = g2<g3?g2:g3;
    unsigned long long g  = ga<gb2?ga:gb2;
    int i = (int)((g>>8)&0xFF);
    int j = (int)(g&0xFF);
    float ni = sizes[i], nj = sizes[j];
    // --- phase C/D: Lance-Williams update + incremental rowkey (round-8 logic) ---
    int k=tid;
    if(k<T_){
      float di=D[i][k], dj=D[j][k];
      unsigned long long oldkey = rowkey[k];
      float oldrm = unpackval(oldkey);
      int oldarg = (int)(oldkey & 0xFF);
      bool kact = (k!=i) && (k!=j) && (active[k]!=0);
      float nd = kact ? (ni*di + nj*dj) / (ni+nj) : INF_;
      D[i][k]=nd; D[k][i]=nd; D[j][k]=INF_; D[k][j]=INF_;
      if(labels[k]==j) labels[k]=i;
      if(k==i){
        int q=atomicAdd(&rcnt,1); rlist[q]=k;                 // row i: full rescan
      } else if(k==j){
        rowkey[k] = packkey(INF_, k, 0);
      } else if(kact){
        if(oldarg==i){
          if(nd<=oldrm) rowkey[k] = packkey(nd, k, i);
          else { int q=atomicAdd(&rcnt,1); rlist[q]=k; }
        } else if(oldarg==j){
          if(nd<=oldrm) rowkey[k] = packkey(nd, k, i);
          else { int q=atomicAdd(&rcnt,1); rlist[q]=k; }
        } else {
          if(nd<oldrm || (nd==oldrm && i<oldarg)) rowkey[k] = packkey(nd, k, i);
        }
      }
    }
    if(tid==0){ sizes[i]=ni+nj; active[j]=0; }
    if(l==0) atomicExch(&gkey[p^1][w], ~0ULL);   // reset other parity (own wave slot)
    __syncthreads();                   // b2: D/rlist writes visible for rescans
    // --- phase E: rescans via per-wave wave-local atomicMin (no extra barrier) ---
    int nr = rcnt;
    for(int q=w; q<nr; q+=4){
      int rr = rlist[q];
      if(l==0) atomicExch(&scratch[w], ~0ULL);   // ordered before ds_min (wave FIFO)
      unsigned long long lk = ~0ULL;
      for(int cc=l; cc<T_; cc+=64){
        unsigned long long ck = packkey(D[rr][cc], rr, cc);
        if(ck<lk) lk=ck;                          // ascending cc -> first col on ties
      }
      atomicMin(&scratch[w], lk);
      LGKM0();
      unsigned long long rk = scratch[w];
      if(l==0) rowkey[rr] = rk;
    }
    __syncthreads();                   // b3: rowkey/rescan writes visible for next A
  }

  if(tid==0){
    int c=0;
    for(int t=0;t<T_;t++){ c += active[t]; rlist[t]=c-1; }    // rlist = rank now
    labs_ws[b*N_]=0; labs_out[b*N_]=0.0f;
  }
  __syncthreads();
  for(int t=tid;t<T_;t+=256){
    int lab = rlist[labels[t]] + 1;
    labs_ws[b*N_+1+t] = lab;
    labs_out[b*N_+1+t] = (float)lab;
  }
}

// ---------------- weighted-average merge: one block per (chunk of 256 ch, b) ----------------
__global__ __launch_bounds__(256) void merge_kernel(const float* __restrict__ x1,
    const float* __restrict__ asz, const int* __restrict__ labs,
    float* __restrict__ x2, float* __restrict__ size_out){
  int chunk = blockIdx.x;     // 0..2 (C_/256)
  int b = blockIdx.y;
  __shared__ float acc[KT_][256];
  __shared__ int   lab[N_];
  __shared__ float sz[N_];
  __shared__ float ssum[KT_];
  int tid = threadIdx.x;
  for(int t=tid;t<N_;t+=256){ lab[t]=labs[b*N_+t]; sz[t]=asz[b*N_+t]; }
#pragma unroll
  for(int k=0;k<KT_;k++) acc[k][tid]=0.f;
  __syncthreads();
  if(tid<KT_){
    float s=0.f;
    for(int n=0;n<N_;n++) if(lab[n]==tid) s += sz[n];
    ssum[tid]=s;
  }
  int c = chunk*256 + tid;
  const float* xb = x1 + (size_t)b*N_*C_ + c;
  for(int n=0;n<N_;n++){
    float v = xb[(size_t)n*C_];
    int k = lab[n];
    acc[k][tid] += v * sz[n];
  }
  __syncthreads();
  for(int k=0;k<KT_;k++)
    x2[((size_t)(b*KT_+k))*C_ + c] = acc[k][tid] / ssum[k];
  if(chunk==0 && tid<KT_) size_out[b*KT_+tid] = ssum[tid];
}

extern "C" void kernel_launch(void* const* d_in, const int* in_sizes, int n_in,
                              void* d_out, int out_size, void* d_ws, size_t ws_size,
                              hipStream_t stream){
  const float* x      = (const float*)d_in[0];
  const float* asz    = (const float*)d_in[1];
  const float* n1_g   = (const float*)d_in[2];
  const float* n1_b   = (const float*)d_in[3];
  const float* w_qkv  = (const float*)d_in[4];
  const float* w_proj = (const float*)d_in[5];
  const float* b_proj = (const float*)d_in[6];
  const float* n2_g   = (const float*)d_in[7];
  const float* n2_b   = (const float*)d_in[8];
  const float* w_fc1  = (const float*)d_in[9];
  const float* b_fc1  = (const float*)d_in[10];
  const float* w_fc2  = (const float*)d_in[11];
  const float* b_fc2  = (const float*)d_in[12];

  const size_t ROWS = (size_t)B_*N_;        // 12608
  const size_t M2   = (size_t)B_*KT_;       // 6336
  float* ws = (float*)d_ws;

  float* h     = ws;                                    // [ROWS*C] f32 LN1 out; later x1
  float* qkvR  = h + ROWS*C_;                           // region, ROWS*3C floats
  __hip_bfloat16* qkvb = (__hip_bfloat16*)qkvR;         // qkv as bf16 (attn-only consumer)
  float* x2    = qkvR;                                  // [M2*C] alias (qkv dead by merge)
  __hip_bfloat16* h2b = (__hip_bfloat16*)(qkvR + M2*C_);
  __hip_bfloat16* h3b = (__hip_bfloat16*)(qkvR + M2*C_ + M2*C_/2);
  __hip_bfloat16* hb  = (__hip_bfloat16*)(qkvR + ROWS*3*C_);      // [ROWS*C] bf16; later xa
  __hip_bfloat16* xa  = hb;
  float* mnorm = (float*)(hb) + ROWS*C_/2;
  float* Wm    = mnorm + (size_t)B_*T_*64;
  __hip_bfloat16* wqkvT = (__hip_bfloat16*)(Wm + C_*64);
  __hip_bfloat16* wprojT= (__hip_bfloat16*)((float*)wqkvT + (size_t)3*C_*C_/2);
  __hip_bfloat16* wfc1T = (__hip_bfloat16*)((float*)wprojT + (size_t)C_*C_/2);
  __hip_bfloat16* wfc2T = (__hip_bfloat16*)((float*)wfc1T + (size_t)C_*HF_/2);
  int*   labs  = (int*)((float*)wfc2T + (size_t)HF_*C_/2);
  float* x1    = h;

  float* out     = (float*)d_out;
  float* out_sz  = out + M2*C_;
  float* out_lab = out_sz + M2;

  // prep
  ln_kernel<<<dim3((unsigned)ROWS),256,0,stream>>>(x, n1_g, n1_b, h, hb);
  wmean_kernel<<<dim3(192),256,0,stream>>>(w_qkv, Wm);
  transpose_bf16<<<dim3(72,24),256,0,stream>>>(w_qkv, wqkvT, C_, 3*C_);
  transpose_bf16<<<dim3(24,24),256,0,stream>>>(w_proj, wprojT, C_, C_);
  transpose_bf16<<<dim3(96,24),256,0,stream>>>(w_fc1, wfc1T, C_, HF_);
  transpose_bf16<<<dim3(24,96),256,0,stream>>>(w_fc2, wfc2T, HF_, C_);

  // attention block
  gemm_bf16<4><<<dim3(18,99),256,0,stream>>>((const ushort*)hb, (const ushort*)wqkvT,
      nullptr, nullptr, qkvb, (int)ROWS, 3*C_, C_);
  metric_gemm<<<dim3(788),256,0,stream>>>(h, Wm, mnorm);
  attn_mfma<<<dim3(H_,B_),256,0,stream>>>((const ushort*)qkvb, asz, xa);
  gemm_bf16<1><<<dim3(6,99),256,0,stream>>>((const ushort*)xa, (const ushort*)wprojT,
      b_proj, x, x1, (int)ROWS, C_, C_);

  // clustering + merge
  cluster_kernel<<<dim3(B_),256,0,stream>>>(mnorm, labs, out_lab);
  merge_kernel<<<dim3(3,B_),256,0,stream>>>(x1, asz, labs, x2, out_sz);

  // MLP
  ln_kernel<<<dim3((unsigned)M2),256,0,stream>>>(x2, n2_g, n2_b, nullptr, h2b);
  gemm_bf16<2><<<dim3(24,50),256,0,stream>>>((const ushort*)h2b, (const ushort*)wfc1T,
      b_fc1, nullptr, h3b, (int)M2, HF_, C_);
  gemm_bf16<3><<<dim3(6,50),256,0,stream>>>((const ushort*)h3b, (const ushort*)wfc2T,
      b_fc2, x2, out, (int)M2, C_, HF_);
}